// Round 1
// baseline (370.299 us; speedup 1.0000x reference)
//
#include <hip/hip_runtime.h>
#include <stdint.h>

typedef unsigned int u32;

#define N_ITEMS 131072
#define CHUNK 64
#define NCHUNKS (N_ITEMS / CHUNK)     // 2048
#define MERGE_LEVELS 11               // log2(NCHUNKS)
#define SORT_BLOCKS 256
#define SORT_THREADS 512
#define HIST_SIZE (256 * SORT_BLOCKS) // 65536

// ---------- helpers ----------

__device__ __forceinline__ float lae(float a, float b) {
  // logaddexp, stable
  float m = fmaxf(a, b);
  float d = fabsf(a - b);
  return m + log1pf(expf(-d));
}

// sum_{i=s}^{e} (N - i) = (e-s+1) * (2N - s - e) / 2   (exact weight-side sum-exp)
__device__ __forceinline__ float wsumf(int s, int e) {
  return 0.5f * (float)(e - s + 1) * (float)(2 * N_ITEMS - s - e);
}

__device__ __forceinline__ float key_to_score(u32 key) {
  u32 m = ~key;
  u32 u = (m & 0x80000000u) ? (m ^ 0x80000000u) : ~m;
  return __uint_as_float(u);
}

// ---------- 1) scores + sort keys ----------

__global__ void score_key_kernel(const float* __restrict__ x,
                                 const float* __restrict__ w1,
                                 const float* __restrict__ b1,
                                 const float* __restrict__ w2,
                                 const float* __restrict__ b2,
                                 u32* __restrict__ key, u32* __restrict__ idx) {
  int i = blockIdx.x * blockDim.x + threadIdx.x;
  if (i >= N_ITEMS) return;
  float xv = x[i];
  float s = b2[0];
#pragma unroll
  for (int j = 0; j < 32; ++j) {
    float h = fmaf(xv, w1[j], b1[j]);
    h = fmaxf(h, 0.0f);
    s = fmaf(h, w2[j], s);
  }
  u32 u = __float_as_uint(s);
  // ascending-order map then invert -> ascending key == descending score
  u32 m = u ^ ((u & 0x80000000u) ? 0xFFFFFFFFu : 0x80000000u);
  key[i] = ~m;
  idx[i] = (u32)i;
}

// ---------- 2) LSD radix sort (stable), 4 x 8-bit ----------

__global__ void hist_kernel(const u32* __restrict__ keyIn, u32* __restrict__ hist,
                            int shift) {
  __shared__ u32 h[256];
  int t = threadIdx.x;
  if (t < 256) h[t] = 0u;
  __syncthreads();
  int g = blockIdx.x * SORT_THREADS + t;
  u32 b = (keyIn[g] >> shift) & 255u;
  atomicAdd(&h[b], 1u);
  __syncthreads();
  if (t < 256) hist[t * SORT_BLOCKS + blockIdx.x] = h[t];
}

__global__ void scan_kernel(u32* __restrict__ hist) {
  // exclusive scan of HIST_SIZE entries, 1 block x 1024 threads, 64 per thread
  __shared__ u32 sums[1024];
  int t = threadIdx.x;
  int base = t * (HIST_SIZE / 1024);
  u32 s = 0;
  for (int k = 0; k < HIST_SIZE / 1024; ++k) s += hist[base + k];
  sums[t] = s;
  __syncthreads();
  for (int off = 1; off < 1024; off <<= 1) {
    u32 v = (t >= off) ? sums[t - off] : 0u;
    __syncthreads();
    sums[t] += v;
    __syncthreads();
  }
  u32 run = (t == 0) ? 0u : sums[t - 1];
  for (int k = 0; k < HIST_SIZE / 1024; ++k) {
    u32 v = hist[base + k];
    hist[base + k] = run;
    run += v;
  }
}

__global__ void scatter_kernel(const u32* __restrict__ keyIn, const u32* __restrict__ idxIn,
                               u32* __restrict__ keyOut, u32* __restrict__ idxOut,
                               const u32* __restrict__ hist, int shift) {
  __shared__ u32 k0[512], k1[512], i0[512], i1[512];
  __shared__ u32 scanbuf[512];
  __shared__ u32 hcount[256];
  int t = threadIdx.x;
  int g = blockIdx.x * SORT_THREADS + t;
  k0[t] = keyIn[g];
  i0[t] = idxIn[g];
  __syncthreads();
  u32 *ks = k0, *kd = k1, *is = i0, *id = i1;
  // 8 x stable 1-bit splits => block locally sorted by digit, stable
  for (int bit = 0; bit < 8; ++bit) {
    u32 kk = ks[t], ii = is[t];
    u32 pred = (kk >> (shift + bit)) & 1u;
    scanbuf[t] = pred;
    __syncthreads();
    for (int off = 1; off < 512; off <<= 1) {
      u32 v = (t >= off) ? scanbuf[t - off] : 0u;
      __syncthreads();
      scanbuf[t] += v;
      __syncthreads();
    }
    u32 onesExcl = scanbuf[t] - pred;
    u32 totalOnes = scanbuf[511];
    u32 zeros = 512u - totalOnes;
    u32 pos = pred ? (zeros + onesExcl) : ((u32)t - onesExcl);
    kd[pos] = kk;
    id[pos] = ii;
    __syncthreads();
    u32* tmp;
    tmp = ks; ks = kd; kd = tmp;
    tmp = is; is = id; id = tmp;
  }
  // bin starts within block
  if (t < 256) hcount[t] = 0u;
  __syncthreads();
  u32 kk = ks[t];
  u32 b = (kk >> shift) & 255u;
  atomicAdd(&hcount[b], 1u);
  __syncthreads();
  if (t < 256) scanbuf[t] = hcount[t];
  __syncthreads();
  for (int off = 1; off < 256; off <<= 1) {
    u32 v = 0u;
    if (t >= off && t < 256) v = scanbuf[t - off];
    __syncthreads();
    if (t < 256) scanbuf[t] += v;
    __syncthreads();
  }
  u32 binStartLocal = scanbuf[b] - hcount[b]; // exclusive
  u32 within = (u32)t - binStartLocal;
  u32 gpos = hist[b * SORT_BLOCKS + blockIdx.x] + within;
  keyOut[gpos] = kk;
  idxOut[gpos] = is[t];
}

// ---------- 3) PAV: per-chunk sequential + tree merge ----------
// Block record k in a region starting at chunk c: slots base=c*CHUNK.
//   ly[k]  = logsumexp of y over block
//   valv[k]= ly - log(sum of (N-i) over block)   (pooled KL value)
//   se[k]  = (start, end) inclusive sorted-position range

__global__ void pav_chunk_kernel(const u32* __restrict__ keyS,
                                 float* __restrict__ ly, float* __restrict__ valv,
                                 int2* __restrict__ se, int* __restrict__ cnt) {
  int c = blockIdx.x * blockDim.x + threadIdx.x;
  if (c >= NCHUNKS) return;
  int base = c * CHUNK;
  int ptr = 0;
  for (int k = 0; k < CHUNK; ++k) {
    int i = base + k;
    float s = key_to_score(keyS[i]);
    float nly = s;
    int ns = i, ne = i;
    float nval = s - logf((float)(N_ITEMS - i));
    while (ptr > 0) {
      float pv = valv[base + ptr - 1];
      if (!(pv <= nval)) break;           // merge while prev <= cur (ref semantics)
      nly = lae(ly[base + ptr - 1], nly);
      ns = se[base + ptr - 1].x;
      nval = nly - logf(wsumf(ns, ne));
      --ptr;
    }
    ly[base + ptr] = nly;
    valv[base + ptr] = nval;
    se[base + ptr] = make_int2(ns, ne);
    ++ptr;
  }
  cnt[c] = ptr;
}

__global__ void merge_kernel(float* __restrict__ ly, float* __restrict__ valv,
                             int2* __restrict__ se, int* __restrict__ cnt, int level) {
  __shared__ int sh_a, sh_b, sh_hasM, sh_nL, sh_nR;
  __shared__ float sh_Mly, sh_Mval;
  __shared__ int sh_Ms, sh_Me;
  int leftChunk = blockIdx.x << (level + 1);
  int rightChunk = leftChunk + (1 << level);
  int base = leftChunk * CHUNK;
  int rbase = rightChunk * CHUNK;
  if (threadIdx.x == 0) {
    int nL = cnt[leftChunk], nR = cnt[rightChunk];
    int a = 0, b = 0, hasM = 0;
    float Mly = 0.f, Mval = 0.f;
    int Ms = 0, Me = 0;
    float tv = valv[base + nL - 1];
    float rv = valv[rbase];
    if (tv <= rv) {
      // single straddling pooled block M (PAV confluence: only boundary violates)
      hasM = 1;
      Mly = lae(ly[base + nL - 1], ly[rbase]);
      Ms = se[base + nL - 1].x;
      Me = se[rbase].y;
      Mval = Mly - logf(wsumf(Ms, Me));
      a = 1; b = 1;
      for (;;) {
        if (a < nL && valv[base + nL - 1 - a] <= Mval) {
          Mly = lae(ly[base + nL - 1 - a], Mly);
          Ms = se[base + nL - 1 - a].x;
          Mval = Mly - logf(wsumf(Ms, Me));
          ++a;
        } else if (b < nR && Mval <= valv[rbase + b]) {
          Mly = lae(Mly, ly[rbase + b]);
          Me = se[rbase + b].y;
          Mval = Mly - logf(wsumf(Ms, Me));
          ++b;
        } else break;
      }
    }
    sh_a = a; sh_b = b; sh_hasM = hasM; sh_nL = nL; sh_nR = nR;
    sh_Mly = Mly; sh_Mval = Mval; sh_Ms = Ms; sh_Me = Me;
  }
  __syncthreads();
  int a = sh_a, b = sh_b, hasM = sh_hasM, nL = sh_nL, nR = sh_nR;
  int destBase = base + (nL - a) + hasM;
  int srcBase = rbase + b;
  int ncopy = nR - b;
  // staged parallel compaction; destBase <= srcBase so future reads never clobbered
  for (int off = 0; off < ncopy; off += blockDim.x) {
    int k = off + (int)threadIdx.x;
    float cl = 0.f, cv = 0.f;
    int2 cse = make_int2(0, 0);
    bool act = (k < ncopy);
    if (act) { cl = ly[srcBase + k]; cv = valv[srcBase + k]; cse = se[srcBase + k]; }
    __syncthreads();
    if (act) { ly[destBase + k] = cl; valv[destBase + k] = cv; se[destBase + k] = cse; }
    __syncthreads();
  }
  if (threadIdx.x == 0) {
    if (hasM) {
      int p = base + (nL - a); // never a copy source/dest
      ly[p] = sh_Mly; valv[p] = sh_Mval; se[p] = make_int2(sh_Ms, sh_Me);
    }
    cnt[leftChunk] = (nL - a) + hasM + ncopy;
  }
}

// ---------- 4) ranks + final transform + scatter ----------

__global__ void out_kernel(const u32* __restrict__ keyS, const u32* __restrict__ idxS,
                           const float* __restrict__ valv, const int2* __restrict__ se,
                           const int* __restrict__ cnt, float* __restrict__ out) {
  int i = blockIdx.x * blockDim.x + threadIdx.x;
  if (i >= N_ITEMS) return;
  int m = cnt[0];
  // largest k with se[k].x <= i
  int lo = 0, hi = m - 1;
  while (lo < hi) {
    int mid = (lo + hi + 1) >> 1;
    if (se[mid].x <= i) lo = mid;
    else hi = mid - 1;
  }
  float sol = valv[lo];
  float s = key_to_score(keyS[i]);
  float rank = expf(s - sol);
  // (ranks - ranks % 3) / 3 + 1 == floor(ranks/3) + 1  for ranks > 0
  float r = floorf(rank / 3.0f) + 1.0f;
  out[idxS[i]] = r;
}

// ---------- launch ----------

extern "C" void kernel_launch(void* const* d_in, const int* in_sizes, int n_in,
                              void* d_out, int out_size, void* d_ws, size_t ws_size,
                              hipStream_t stream) {
  const float* x  = (const float*)d_in[0];
  const float* w1 = (const float*)d_in[1];
  const float* b1 = (const float*)d_in[2];
  const float* w2 = (const float*)d_in[3];
  const float* b2 = (const float*)d_in[4];
  float* out = (float*)d_out;

  char* ws = (char*)d_ws;
  size_t o = 0;
  u32* keyA = (u32*)(ws + o); o += (size_t)N_ITEMS * 4;
  u32* keyB = (u32*)(ws + o); o += (size_t)N_ITEMS * 4;
  u32* idxA = (u32*)(ws + o); o += (size_t)N_ITEMS * 4;
  u32* idxB = (u32*)(ws + o); o += (size_t)N_ITEMS * 4;
  u32* hist = (u32*)(ws + o); o += (size_t)HIST_SIZE * 4;
  float* ly   = (float*)(ws + o); o += (size_t)N_ITEMS * 4;
  float* valv = (float*)(ws + o); o += (size_t)N_ITEMS * 4;
  int2* se    = (int2*)(ws + o);  o += (size_t)N_ITEMS * 8;
  int* cnt    = (int*)(ws + o);   o += (size_t)NCHUNKS * 4;

  score_key_kernel<<<N_ITEMS / 256, 256, 0, stream>>>(x, w1, b1, w2, b2, keyA, idxA);

  u32 *kin = keyA, *kout = keyB, *iin = idxA, *iout = idxB;
  for (int p = 0; p < 4; ++p) {
    int shift = p * 8;
    hist_kernel<<<SORT_BLOCKS, SORT_THREADS, 0, stream>>>(kin, hist, shift);
    scan_kernel<<<1, 1024, 0, stream>>>(hist);
    scatter_kernel<<<SORT_BLOCKS, SORT_THREADS, 0, stream>>>(kin, iin, kout, iout, hist, shift);
    u32* t;
    t = kin; kin = kout; kout = t;
    t = iin; iin = iout; iout = t;
  }
  // after 4 passes sorted data is back in keyA/idxA (== kin/iin)

  pav_chunk_kernel<<<NCHUNKS / 256, 256, 0, stream>>>(kin, ly, valv, se, cnt);

  for (int lvl = 0; lvl < MERGE_LEVELS; ++lvl) {
    int tasks = NCHUNKS >> (lvl + 1);
    merge_kernel<<<tasks, 256, 0, stream>>>(ly, valv, se, cnt, lvl);
  }

  out_kernel<<<N_ITEMS / 256, 256, 0, stream>>>(kin, iin, valv, se, cnt, out);
}

// Round 2
// 251.219 us; speedup vs baseline: 1.4740x; 1.4740x over previous
//
#include <hip/hip_runtime.h>
#include <stdint.h>

typedef unsigned int u32;

#define N_ITEMS 131072
#define NB 131072                   // sort buckets
#define CHUNK 64
#define NCHUNKS (N_ITEMS / CHUNK)   // 2048

// ---------- helpers ----------

// sum_{i=s}^{e} (N - i) = (e-s+1)*(2N-s-e)/2  — exact weight-side sum of exp(w)
__device__ __forceinline__ float wsumf(int s, int e) {
  return 0.5f * (float)(e - s + 1) * (float)(2 * N_ITEMS - s - e);
}

__device__ __forceinline__ float key_to_score(u32 key) {
  u32 m = ~key;
  u32 u = (m & 0x80000000u) ? (m ^ 0x80000000u) : ~m;
  return __uint_as_float(u);
}

#define LOG2E 1.4426950408889634f
__device__ __forceinline__ float fexp(float x) { return exp2f(x * LOG2E); }

__device__ __forceinline__ u32 bucket_of(u32 key, u32 kmin, u32 kmax) {
  double scale = (double)NB / ((double)(kmax - kmin) + 1.0);
  u32 b = (u32)((double)(key - kmin) * scale);
  return b < NB ? b : (NB - 1);
}

// ---------- 1) scores + descending-order keys + key min/max ----------

__global__ void score_key_kernel(const float* __restrict__ x,
                                 const float* __restrict__ w1,
                                 const float* __restrict__ b1,
                                 const float* __restrict__ w2,
                                 const float* __restrict__ b2,
                                 u32* __restrict__ keyRaw, u32* __restrict__ minmax) {
  __shared__ u32 rmin[256], rmax[256];
  int t = threadIdx.x;
  int i = blockIdx.x * 256 + t;
  float xv = x[i];
  float s = b2[0];
#pragma unroll
  for (int j = 0; j < 32; ++j) {
    float h = fmaf(xv, w1[j], b1[j]);
    h = fmaxf(h, 0.0f);
    s = fmaf(h, w2[j], s);
  }
  u32 u = __float_as_uint(s);
  u32 m = u ^ ((u & 0x80000000u) ? 0xFFFFFFFFu : 0x80000000u); // ascending map
  u32 key = ~m;                                                // ascending key == descending score
  keyRaw[i] = key;
  rmin[t] = key; rmax[t] = key;
  __syncthreads();
  for (int off = 128; off > 0; off >>= 1) {
    if (t < off) {
      rmin[t] = min(rmin[t], rmin[t + off]);
      rmax[t] = max(rmax[t], rmax[t + off]);
    }
    __syncthreads();
  }
  if (t == 0) {
    atomicMin(&minmax[0], rmin[0]);
    atomicMax(&minmax[1], rmax[0]);
  }
}

// ---------- 2) approximate bucket sort: hist -> scan -> atomic scatter ----------

__global__ void bucket_hist_kernel(const u32* __restrict__ keyRaw,
                                   const u32* __restrict__ minmax,
                                   u32* __restrict__ hist) {
  int i = blockIdx.x * 256 + threadIdx.x;
  u32 b = bucket_of(keyRaw[i], minmax[0], minmax[1]);
  atomicAdd(&hist[b], 1u);
}

__global__ __launch_bounds__(1024) void scan_hist_kernel(u32* __restrict__ hist) {
  __shared__ u32 sums[1024];
  int t = threadIdx.x;
  const int PER4 = NB / 1024 / 4;  // 32 uint4 per thread
  uint4* h4 = (uint4*)hist;
  int b4 = t * PER4;
  u32 s = 0;
  for (int k = 0; k < PER4; ++k) {
    uint4 v = h4[b4 + k];
    s += v.x + v.y + v.z + v.w;
  }
  sums[t] = s;
  __syncthreads();
  for (int off = 1; off < 1024; off <<= 1) {
    u32 v = (t >= off) ? sums[t - off] : 0u;
    __syncthreads();
    sums[t] += v;
    __syncthreads();
  }
  u32 run = (t == 0) ? 0u : sums[t - 1];
  for (int k = 0; k < PER4; ++k) {
    uint4 v = h4[b4 + k];
    uint4 o;
    o.x = run; run += v.x;
    o.y = run; run += v.y;
    o.z = run; run += v.z;
    o.w = run; run += v.w;
    h4[b4 + k] = o;
  }
}

__global__ void bucket_scatter_kernel(const u32* __restrict__ keyRaw,
                                      const u32* __restrict__ minmax,
                                      u32* __restrict__ hist,
                                      u32* __restrict__ keyS, u32* __restrict__ idxS) {
  int i = blockIdx.x * 256 + threadIdx.x;
  u32 key = keyRaw[i];
  u32 b = bucket_of(key, minmax[0], minmax[1]);
  u32 pos = atomicAdd(&hist[b], 1u);   // scanned start doubles as running counter
  keyS[pos] = key;
  idxS[pos] = i;
}

// ---------- 3) PAV, linear domain ----------
// Block record: SY = sum of exp(s - smax) over block, ST = start index.
// Ends are implicit (blocks tile [0,N)). val_a <= val_b  <=>  SY_a*SW_b <= SY_b*SW_a.

__global__ __launch_bounds__(64) void pav_chunk_kernel(const u32* __restrict__ keyS,
                                                       const u32* __restrict__ minmax,
                                                       float* __restrict__ SY,
                                                       int* __restrict__ ST,
                                                       int* __restrict__ cnt) {
  __shared__ float sc[64][65];      // exp(s - smax), [within-chunk k][chunk lane]
  __shared__ int   stk_st[64][64];  // [slot][lane]
  __shared__ float stk_sy[64][64];
  int t = threadIdx.x;
  int cBase = blockIdx.x * 4096;    // 64 chunks of 64 per block
  float smax = key_to_score(minmax[0]);
  // coalesced staging: iter r loads element cBase + r*64 + t -> k=t, lane=r
  for (int r = 0; r < 64; ++r) {
    float s = key_to_score(keyS[cBase + r * 64 + t]);
    sc[t][r] = fexp(s - smax);
  }
  __syncthreads();
  int base = cBase + t * 64;        // my chunk's element base
  int ptr = 0;                      // entries below the register-cached top
  float syT = sc[0][t];
  int stT = base;
  for (int k = 1; k < 64; ++k) {
    int i = base + k;
    float syC = sc[k][t];
    int stC = i;
    bool have = true;
    for (;;) {
      float SWc = wsumf(stC, i);
      float SWt = wsumf(stT, stC - 1);
      if (!(syT * SWc <= syC * SWt)) break;   // merge while val_top <= val_cur
      syC += syT; stC = stT;
      if (ptr == 0) { have = false; break; }
      --ptr;
      stT = stk_st[ptr][t]; syT = stk_sy[ptr][t];
    }
    if (have) { stk_st[ptr][t] = stT; stk_sy[ptr][t] = syT; ++ptr; }
    stT = stC; syT = syC;
  }
  for (int k = 0; k < ptr; ++k) {
    ST[base + k] = stk_st[k][t];
    SY[base + k] = stk_sy[k][t];
  }
  ST[base + ptr] = stT;
  SY[base + ptr] = syT;
  cnt[blockIdx.x * 64 + t] = ptr + 1;
}

// ---------- multi-level tree merge: L sub-levels per launch ----------

__global__ void merge_multi_kernel(float* __restrict__ SY, int* __restrict__ ST,
                                   int* __restrict__ cnt, int l0, int L) {
  __shared__ int lcnt[16];
  __shared__ int ca[8], cb[8], cM[8];
  int t = threadIdx.x;
  int G = 1 << L;                   // incoming groups per block
  int S = CHUNK << l0;              // elements per incoming group
  int baseE = blockIdx.x * G * S;   // element base of this block's region
  int baseC = baseE / CHUNK;        // chunk index base
  int strideC = S / CHUNK;
  if (t < G) lcnt[t] = cnt[baseC + t * strideC];
  __syncthreads();
  for (int j = 0; j < L; ++j) {
    int P = G >> (j + 1);           // pairs this sub-level
    if (t < P) {
      int p = t;
      int kL = p << (j + 1);
      int kR = kL + (1 << j);
      int baseL = baseE + kL * S;
      int baseR = baseE + kR * S;
      int rend = baseR + (1 << j) * S - 1;
      int nL = lcnt[kL], nR = lcnt[kR];
      int a = 0, b = 0, hasM = 0;
      float SYL = SY[baseL + nL - 1];
      int stL = ST[baseL + nL - 1];
      float SYR = SY[baseR];
      int eR = (nR > 1) ? (ST[baseR + 1] - 1) : rend;
      float SWL = wsumf(stL, baseR - 1);
      float SWR = wsumf(baseR, eR);
      if (SYL * SWR <= SYR * SWL) {
        hasM = 1;
        float SYM = SYL + SYR;
        int Ms = stL, Me = eR;
        a = 1; b = 1;
        for (;;) {
          float SWM = wsumf(Ms, Me);
          if (a < nL) {
            float SYe = SY[baseL + nL - 1 - a];
            int ste = ST[baseL + nL - 1 - a];
            float SWe = wsumf(ste, Ms - 1);
            if (SYe * SWM <= SYM * SWe) { SYM += SYe; Ms = ste; ++a; continue; }
          }
          if (b < nR) {
            float SYb = SY[baseR + b];
            int sb = ST[baseR + b];
            int eb = (b + 1 < nR) ? (ST[baseR + b + 1] - 1) : rend;
            float SWb = wsumf(sb, eb);
            if (SYM * SWb <= SYb * SWM) { SYM += SYb; Me = eb; ++b; continue; }
          }
          break;
        }
        SY[baseL + nL - a] = SYM;   // M slot: below baseR, never a copy src/dest
        ST[baseL + nL - a] = Ms;
      }
      ca[p] = a; cb[p] = b; cM[p] = hasM;
    }
    __threadfence_block();
    __syncthreads();
    // compaction copies: pair-sequential, whole block, staged (dest <= src)
    for (int p = 0; p < P; ++p) {
      int kL = p << (j + 1);
      int kR = kL + (1 << j);
      int nL = lcnt[kL], nR = lcnt[kR];
      int a = ca[p], b = cb[p], hasM = cM[p];
      int baseL = baseE + kL * S;
      int baseR = baseE + kR * S;
      int destBase = baseL + nL - a + hasM;
      int srcBase = baseR + b;
      int ncopy = nR - b;
      for (int off = 0; off < ncopy; off += blockDim.x) {
        int k2 = off + t;
        bool act = k2 < ncopy;
        float vs = 0.f; int vt = 0;
        if (act) { vs = SY[srcBase + k2]; vt = ST[srcBase + k2]; }
        __syncthreads();
        if (act) { SY[destBase + k2] = vs; ST[destBase + k2] = vt; }
        __threadfence_block();
        __syncthreads();
      }
    }
    __syncthreads();
    if (t < P) {
      int p = t;
      int kL = p << (j + 1);
      int kR = kL + (1 << j);
      lcnt[kL] = lcnt[kL] - ca[p] + cM[p] + (lcnt[kR] - cb[p]);
    }
    __threadfence_block();
    __syncthreads();
  }
  if (t == 0) cnt[baseC] = lcnt[0];
}

// ---------- 4) ranks + transform + scatter ----------

__global__ void out_kernel(const u32* __restrict__ keyS, const u32* __restrict__ idxS,
                           const float* __restrict__ SY, const int* __restrict__ ST,
                           const int* __restrict__ cnt, const u32* __restrict__ minmax,
                           float* __restrict__ out) {
  int i = blockIdx.x * 256 + threadIdx.x;
  int m = cnt[0];
  float smax = key_to_score(minmax[0]);
  int lo = 0, hi = m - 1;
  while (lo < hi) {
    int mid = (lo + hi + 1) >> 1;
    if (ST[mid] <= i) lo = mid; else hi = mid - 1;
  }
  int s0 = ST[lo];
  int e0 = (lo + 1 < m) ? (ST[lo + 1] - 1) : (N_ITEMS - 1);
  float SW = wsumf(s0, e0);
  float s = key_to_score(keyS[i]);
  float rank = fexp(s - smax) * SW / SY[lo];
  out[idxS[i]] = floorf(rank * (1.0f / 3.0f)) + 1.0f;
}

// ---------- launch ----------

extern "C" void kernel_launch(void* const* d_in, const int* in_sizes, int n_in,
                              void* d_out, int out_size, void* d_ws, size_t ws_size,
                              hipStream_t stream) {
  const float* x  = (const float*)d_in[0];
  const float* w1 = (const float*)d_in[1];
  const float* b1 = (const float*)d_in[2];
  const float* w2 = (const float*)d_in[3];
  const float* b2 = (const float*)d_in[4];
  float* out = (float*)d_out;

  char* ws = (char*)d_ws;
  size_t o = 0;
  u32* keyRaw = (u32*)(ws + o); o += (size_t)N_ITEMS * 4;
  u32* keyS   = (u32*)(ws + o); o += (size_t)N_ITEMS * 4;
  u32* idxS   = (u32*)(ws + o); o += (size_t)N_ITEMS * 4;
  u32* hist   = (u32*)(ws + o); o += (size_t)NB * 4;
  float* SY   = (float*)(ws + o); o += (size_t)N_ITEMS * 4;
  int* ST     = (int*)(ws + o);   o += (size_t)N_ITEMS * 4;
  int* cnt    = (int*)(ws + o);   o += (size_t)NCHUNKS * 4;
  u32* minmax = (u32*)(ws + o);   o += 16;

  hipMemsetAsync(minmax, 0xFF, 4, stream);            // kmin = 0xFFFFFFFF
  hipMemsetAsync((char*)minmax + 4, 0x00, 4, stream); // kmax = 0
  hipMemsetAsync(hist, 0, (size_t)NB * 4, stream);

  score_key_kernel<<<N_ITEMS / 256, 256, 0, stream>>>(x, w1, b1, w2, b2, keyRaw, minmax);
  bucket_hist_kernel<<<N_ITEMS / 256, 256, 0, stream>>>(keyRaw, minmax, hist);
  scan_hist_kernel<<<1, 1024, 0, stream>>>(hist);
  bucket_scatter_kernel<<<N_ITEMS / 256, 256, 0, stream>>>(keyRaw, minmax, hist, keyS, idxS);

  pav_chunk_kernel<<<NCHUNKS / 64, 64, 0, stream>>>(keyS, minmax, SY, ST, cnt);

  // 11 tree levels in 3 launches: levels 0-3, 4-7, 8-10
  merge_multi_kernel<<<NCHUNKS / 16, 256, 0, stream>>>(SY, ST, cnt, 0, 4);
  merge_multi_kernel<<<NCHUNKS / 256, 256, 0, stream>>>(SY, ST, cnt, 4, 4);
  merge_multi_kernel<<<1, 256, 0, stream>>>(SY, ST, cnt, 8, 3);

  out_kernel<<<N_ITEMS / 256, 256, 0, stream>>>(keyS, idxS, SY, ST, cnt, minmax, out);
}

// Round 3
// 200.275 us; speedup vs baseline: 1.8490x; 1.2544x over previous
//
#include <hip/hip_runtime.h>
#include <stdint.h>

typedef unsigned int u32;

#define N_ITEMS 131072
#define NB 131072                   // sort buckets
#define CHUNK 64
#define NCHUNKS (N_ITEMS / CHUNK)   // 2048
#define SCAN_BLOCKS 512             // NB / 256

// ---------- helpers ----------

// sum_{i=s}^{e} (N - i) = (e-s+1)*(2N-s-e)/2  — exact weight-side sum of exp(w)
__device__ __forceinline__ float wsumf(int s, int e) {
  return 0.5f * (float)(e - s + 1) * (float)(2 * N_ITEMS - s - e);
}

__device__ __forceinline__ float key_to_score(u32 key) {
  u32 m = ~key;
  u32 u = (m & 0x80000000u) ? (m ^ 0x80000000u) : ~m;
  return __uint_as_float(u);
}

#define LOG2E 1.4426950408889634f
__device__ __forceinline__ float fexp(float x) { return exp2f(x * LOG2E); }

__device__ __forceinline__ u32 bucket_of(u32 key, u32 kmin, u32 kmax) {
  double scale = (double)NB / ((double)(kmax - kmin) + 1.0);
  u32 b = (u32)((double)(key - kmin) * scale);
  return b < NB ? b : (NB - 1);
}

// ---------- 1) scores + descending-order keys + key min/max ----------

__global__ void score_key_kernel(const float* __restrict__ x,
                                 const float* __restrict__ w1,
                                 const float* __restrict__ b1,
                                 const float* __restrict__ w2,
                                 const float* __restrict__ b2,
                                 u32* __restrict__ keyRaw, u32* __restrict__ minmax) {
  __shared__ u32 rmin[256], rmax[256];
  int t = threadIdx.x;
  int i = blockIdx.x * 256 + t;
  float xv = x[i];
  float s = b2[0];
#pragma unroll
  for (int j = 0; j < 32; ++j) {
    float h = fmaf(xv, w1[j], b1[j]);
    h = fmaxf(h, 0.0f);
    s = fmaf(h, w2[j], s);
  }
  u32 u = __float_as_uint(s);
  u32 m = u ^ ((u & 0x80000000u) ? 0xFFFFFFFFu : 0x80000000u); // ascending map
  u32 key = ~m;                                                // ascending key == descending score
  keyRaw[i] = key;
  rmin[t] = key; rmax[t] = key;
  __syncthreads();
  for (int off = 128; off > 0; off >>= 1) {
    if (t < off) {
      rmin[t] = min(rmin[t], rmin[t + off]);
      rmax[t] = max(rmax[t], rmax[t + off]);
    }
    __syncthreads();
  }
  if (t == 0) {
    atomicMin(&minmax[0], rmin[0]);
    atomicMax(&minmax[1], rmax[0]);
  }
}

// ---------- 2) approximate bucket sort: hist -> hierarchical scan -> atomic scatter ----------

__global__ void bucket_hist_kernel(const u32* __restrict__ keyRaw,
                                   const u32* __restrict__ minmax,
                                   u32* __restrict__ hist) {
  int i = blockIdx.x * 256 + threadIdx.x;
  u32 b = bucket_of(keyRaw[i], minmax[0], minmax[1]);
  atomicAdd(&hist[b], 1u);
}

__global__ void scan_pass1(const u32* __restrict__ hist, u32* __restrict__ bsum) {
  __shared__ u32 red[256];
  int t = threadIdx.x;
  red[t] = hist[blockIdx.x * 256 + t];
  __syncthreads();
  for (int off = 128; off > 0; off >>= 1) {
    if (t < off) red[t] += red[t + off];
    __syncthreads();
  }
  if (t == 0) bsum[blockIdx.x] = red[0];
}

__global__ __launch_bounds__(512) void scan_pass2(u32* __restrict__ bsum) {
  __shared__ u32 s[512];
  int t = threadIdx.x;
  u32 v = bsum[t];
  s[t] = v;
  __syncthreads();
  for (int off = 1; off < 512; off <<= 1) {
    u32 x = (t >= off) ? s[t - off] : 0u;
    __syncthreads();
    s[t] += x;
    __syncthreads();
  }
  bsum[t] = s[t] - v;   // exclusive
}

__global__ void scan_pass3(u32* __restrict__ hist, const u32* __restrict__ bsum) {
  __shared__ u32 s[256];
  int t = threadIdx.x;
  int i = blockIdx.x * 256 + t;
  u32 v = hist[i];
  s[t] = v;
  __syncthreads();
  for (int off = 1; off < 256; off <<= 1) {
    u32 x = (t >= off) ? s[t - off] : 0u;
    __syncthreads();
    s[t] += x;
    __syncthreads();
  }
  hist[i] = s[t] - v + bsum[blockIdx.x];   // exclusive global prefix
}

__global__ void bucket_scatter_kernel(const u32* __restrict__ keyRaw,
                                      const u32* __restrict__ minmax,
                                      u32* __restrict__ hist,
                                      u32* __restrict__ keyS, u32* __restrict__ idxS) {
  int i = blockIdx.x * 256 + threadIdx.x;
  u32 key = keyRaw[i];
  u32 b = bucket_of(key, minmax[0], minmax[1]);
  u32 pos = atomicAdd(&hist[b], 1u);   // scanned start doubles as running counter
  keyS[pos] = key;
  idxS[pos] = i;
}

// ---------- 3) PAV, linear domain ----------
// Block record: SY = sum of exp(s - smax) over block, ST = start index.
// Ends are implicit (blocks tile [0,N)). val_a <= val_b  <=>  SY_a*SW_b <= SY_b*SW_a.

__global__ __launch_bounds__(64) void pav_chunk_kernel(const u32* __restrict__ keyS,
                                                       const u32* __restrict__ minmax,
                                                       float* __restrict__ SY,
                                                       int* __restrict__ ST,
                                                       int* __restrict__ cnt) {
  __shared__ float sc[64][65];      // exp(s - smax), [within-chunk k][chunk lane]
  __shared__ int   stk_st[64][64];  // [slot][lane]
  __shared__ float stk_sy[64][64];
  int t = threadIdx.x;
  int cBase = blockIdx.x * 4096;    // 64 chunks of 64 per block
  float smax = key_to_score(minmax[0]);
  // coalesced staging: iter r loads element cBase + r*64 + t -> k=t, lane=r
  for (int r = 0; r < 64; ++r) {
    float s = key_to_score(keyS[cBase + r * 64 + t]);
    sc[t][r] = fexp(s - smax);
  }
  __syncthreads();
  int base = cBase + t * 64;        // my chunk's element base
  int ptr = 0;                      // entries below the register-cached top
  float syT = sc[0][t];
  int stT = base;
  for (int k = 1; k < 64; ++k) {
    int i = base + k;
    float syC = sc[k][t];
    int stC = i;
    bool have = true;
    for (;;) {
      float SWc = wsumf(stC, i);
      float SWt = wsumf(stT, stC - 1);
      if (!(syT * SWc <= syC * SWt)) break;   // merge while val_top <= val_cur
      syC += syT; stC = stT;
      if (ptr == 0) { have = false; break; }
      --ptr;
      stT = stk_st[ptr][t]; syT = stk_sy[ptr][t];
    }
    if (have) { stk_st[ptr][t] = stT; stk_sy[ptr][t] = syT; ++ptr; }
    stT = stC; syT = syC;
  }
  for (int k = 0; k < ptr; ++k) {
    ST[base + k] = stk_st[k][t];
    SY[base + k] = stk_sy[k][t];
  }
  ST[base + ptr] = stT;
  SY[base + ptr] = syT;
  cnt[blockIdx.x * 64 + t] = ptr + 1;
}

// ---------- multi-level tree merge: L sub-levels per launch ----------

__global__ void merge_multi_kernel(float* __restrict__ SY, int* __restrict__ ST,
                                   int* __restrict__ cnt, int l0, int L) {
  __shared__ int lcnt[16];
  __shared__ int ca[8], cb[8], cM[8];
  int t = threadIdx.x;
  int G = 1 << L;                   // incoming groups per block
  int S = CHUNK << l0;              // elements per incoming group
  int baseE = blockIdx.x * G * S;   // element base of this block's region
  int baseC = baseE / CHUNK;        // chunk index base
  int strideC = S / CHUNK;
  if (t < G) lcnt[t] = cnt[baseC + t * strideC];
  __syncthreads();
  for (int j = 0; j < L; ++j) {
    int P = G >> (j + 1);           // pairs this sub-level
    if (t < P) {
      int p = t;
      int kL = p << (j + 1);
      int kR = kL + (1 << j);
      int baseL = baseE + kL * S;
      int baseR = baseE + kR * S;
      int rend = baseR + (1 << j) * S - 1;
      int nL = lcnt[kL], nR = lcnt[kR];
      int a = 0, b = 0, hasM = 0;
      float SYL = SY[baseL + nL - 1];
      int stL = ST[baseL + nL - 1];
      float SYR = SY[baseR];
      int eR = (nR > 1) ? (ST[baseR + 1] - 1) : rend;
      float SWL = wsumf(stL, baseR - 1);
      float SWR = wsumf(baseR, eR);
      if (SYL * SWR <= SYR * SWL) {
        hasM = 1;
        float SYM = SYL + SYR;
        int Ms = stL, Me = eR;
        a = 1; b = 1;
        for (;;) {
          float SWM = wsumf(Ms, Me);
          if (a < nL) {
            float SYe = SY[baseL + nL - 1 - a];
            int ste = ST[baseL + nL - 1 - a];
            float SWe = wsumf(ste, Ms - 1);
            if (SYe * SWM <= SYM * SWe) { SYM += SYe; Ms = ste; ++a; continue; }
          }
          if (b < nR) {
            float SYb = SY[baseR + b];
            int sb = ST[baseR + b];
            int eb = (b + 1 < nR) ? (ST[baseR + b + 1] - 1) : rend;
            float SWb = wsumf(sb, eb);
            if (SYM * SWb <= SYb * SWM) { SYM += SYb; Me = eb; ++b; continue; }
          }
          break;
        }
        SY[baseL + nL - a] = SYM;   // M slot: below baseR, never a copy src/dest
        ST[baseL + nL - a] = Ms;
      }
      ca[p] = a; cb[p] = b; cM[p] = hasM;
    }
    __threadfence_block();
    __syncthreads();
    // compaction copies: pair-sequential, whole block, staged (dest <= src)
    for (int p = 0; p < P; ++p) {
      int kL = p << (j + 1);
      int kR = kL + (1 << j);
      int nL = lcnt[kL], nR = lcnt[kR];
      int a = ca[p], b = cb[p], hasM = cM[p];
      int baseL = baseE + kL * S;
      int baseR = baseE + kR * S;
      int destBase = baseL + nL - a + hasM;
      int srcBase = baseR + b;
      int ncopy = nR - b;
      for (int off = 0; off < ncopy; off += blockDim.x) {
        int k2 = off + t;
        bool act = k2 < ncopy;
        float vs = 0.f; int vt = 0;
        if (act) { vs = SY[srcBase + k2]; vt = ST[srcBase + k2]; }
        __syncthreads();
        if (act) { SY[destBase + k2] = vs; ST[destBase + k2] = vt; }
        __threadfence_block();
        __syncthreads();
      }
    }
    __syncthreads();
    if (t < P) {
      int p = t;
      int kL = p << (j + 1);
      int kR = kL + (1 << j);
      lcnt[kL] = lcnt[kL] - ca[p] + cM[p] + (lcnt[kR] - cb[p]);
    }
    __threadfence_block();
    __syncthreads();
  }
  if (t == 0) cnt[baseC] = lcnt[0];
}

// ---------- 4) ranks + transform + scatter ----------

__global__ void out_kernel(const u32* __restrict__ keyS, const u32* __restrict__ idxS,
                           const float* __restrict__ SY, const int* __restrict__ ST,
                           const int* __restrict__ cnt, const u32* __restrict__ minmax,
                           float* __restrict__ out) {
  int i = blockIdx.x * 256 + threadIdx.x;
  int m = cnt[0];
  float smax = key_to_score(minmax[0]);
  int lo = 0, hi = m - 1;
  while (lo < hi) {
    int mid = (lo + hi + 1) >> 1;
    if (ST[mid] <= i) lo = mid; else hi = mid - 1;
  }
  int s0 = ST[lo];
  int e0 = (lo + 1 < m) ? (ST[lo + 1] - 1) : (N_ITEMS - 1);
  float SW = wsumf(s0, e0);
  float s = key_to_score(keyS[i]);
  float rank = fexp(s - smax) * SW / SY[lo];
  out[idxS[i]] = floorf(rank * (1.0f / 3.0f)) + 1.0f;
}

// ---------- launch ----------

extern "C" void kernel_launch(void* const* d_in, const int* in_sizes, int n_in,
                              void* d_out, int out_size, void* d_ws, size_t ws_size,
                              hipStream_t stream) {
  const float* x  = (const float*)d_in[0];
  const float* w1 = (const float*)d_in[1];
  const float* b1 = (const float*)d_in[2];
  const float* w2 = (const float*)d_in[3];
  const float* b2 = (const float*)d_in[4];
  float* out = (float*)d_out;

  char* ws = (char*)d_ws;
  size_t o = 0;
  // [minmax(2) pad(2) | hist(NB) | bsum(SCAN_BLOCKS)] zeroed in one memset
  u32* minmax = (u32*)(ws + o); o += 16;
  u32* hist   = (u32*)(ws + o); o += (size_t)NB * 4;
  u32* bsum   = (u32*)(ws + o); o += (size_t)SCAN_BLOCKS * 4;
  u32* keyRaw = (u32*)(ws + o); o += (size_t)N_ITEMS * 4;
  u32* keyS   = (u32*)(ws + o); o += (size_t)N_ITEMS * 4;
  u32* idxS   = (u32*)(ws + o); o += (size_t)N_ITEMS * 4;
  float* SY   = (float*)(ws + o); o += (size_t)N_ITEMS * 4;
  int* ST     = (int*)(ws + o);   o += (size_t)N_ITEMS * 4;
  int* cnt    = (int*)(ws + o);   o += (size_t)NCHUNKS * 4;

  hipMemsetAsync(minmax, 0x00, 16 + (size_t)NB * 4 + (size_t)SCAN_BLOCKS * 4, stream);
  hipMemsetAsync(minmax, 0xFF, 4, stream);            // kmin = 0xFFFFFFFF

  score_key_kernel<<<N_ITEMS / 256, 256, 0, stream>>>(x, w1, b1, w2, b2, keyRaw, minmax);
  bucket_hist_kernel<<<N_ITEMS / 256, 256, 0, stream>>>(keyRaw, minmax, hist);
  scan_pass1<<<SCAN_BLOCKS, 256, 0, stream>>>(hist, bsum);
  scan_pass2<<<1, 512, 0, stream>>>(bsum);
  scan_pass3<<<SCAN_BLOCKS, 256, 0, stream>>>(hist, bsum);
  bucket_scatter_kernel<<<N_ITEMS / 256, 256, 0, stream>>>(keyRaw, minmax, hist, keyS, idxS);

  pav_chunk_kernel<<<NCHUNKS / 64, 64, 0, stream>>>(keyS, minmax, SY, ST, cnt);

  // 11 tree levels in 3 launches: levels 0-3, 4-7, 8-10
  merge_multi_kernel<<<NCHUNKS / 16, 256, 0, stream>>>(SY, ST, cnt, 0, 4);
  merge_multi_kernel<<<NCHUNKS / 256, 256, 0, stream>>>(SY, ST, cnt, 4, 4);
  merge_multi_kernel<<<1, 256, 0, stream>>>(SY, ST, cnt, 8, 3);

  out_kernel<<<N_ITEMS / 256, 256, 0, stream>>>(keyS, idxS, SY, ST, cnt, minmax, out);
}

// Round 4
// 175.898 us; speedup vs baseline: 2.1052x; 1.1386x over previous
//
#include <hip/hip_runtime.h>
#include <stdint.h>

typedef unsigned int u32;
typedef unsigned long long u64;

#define N_ITEMS 131072
#define NB 131072                   // buckets (monotone in descending score)
#define CHUNK 64
#define NCHUNKS 2048                // NB / CHUNK
#define SCAN_BLOCKS 512             // NB / 256

// ---------- helpers ----------

// sum_{i=s}^{e} (N - i) — exact weight-side sum of exp(w) over sorted positions
__device__ __forceinline__ float wsumf(int s, int e) {
  return 0.5f * (float)(e - s + 1) * (float)(2 * N_ITEMS - s - e);
}

__device__ __forceinline__ float key_to_score(u32 key) {
  u32 m = ~key;
  u32 u = (m & 0x80000000u) ? (m ^ 0x80000000u) : ~m;
  return __uint_as_float(u);
}

#define LOG2E 1.4426950408889634f
__device__ __forceinline__ float fexp(float x) { return exp2f(x * LOG2E); }

// ascending key == descending score; ascending bucket == descending score
__device__ __forceinline__ u32 bucket_of(u32 key, u32 kmin, u32 kmax) {
  double scale = (double)NB / ((double)(kmax - kmin) + 1.0);
  u32 b = (u32)((double)(key - kmin) * scale);
  return b < NB ? b : (NB - 1);
}

// ---------- 1) scores -> keys, min/max, cooperative zeroing ----------

__global__ void score_key_kernel(const float* __restrict__ x,
                                 const float* __restrict__ w1,
                                 const float* __restrict__ b1,
                                 const float* __restrict__ w2,
                                 const float* __restrict__ b2,
                                 u32* __restrict__ keyRaw, u32* __restrict__ mm,
                                 u32* __restrict__ hist, float* __restrict__ sumExp,
                                 u64* __restrict__ flags) {
  __shared__ u32 r0[256], r1[256];
  int t = threadIdx.x;
  int i = blockIdx.x * 256 + t;
  float xv = x[i];
  float s = b2[0];
#pragma unroll
  for (int j = 0; j < 32; ++j) {
    float h = fmaf(xv, w1[j], b1[j]);
    h = fmaxf(h, 0.0f);
    s = fmaf(h, w2[j], s);
  }
  u32 u = __float_as_uint(s);
  u32 m = u ^ ((u & 0x80000000u) ? 0xFFFFFFFFu : 0x80000000u); // ascending map
  u32 key = ~m;
  keyRaw[i] = key;
  // cooperative zero of accumulation buffers (consumed by later dispatches)
  hist[i] = 0u;
  sumExp[i] = 0.0f;
  if (i == 0) hist[NB] = 0u;
  if (i < SCAN_BLOCKS) flags[i] = 0ull;
  // min/max via two atomicMax on zero-initialized slots: mm[0]=max(~key), mm[1]=max(key)
  r0[t] = ~key; r1[t] = key;
  __syncthreads();
  for (int off = 128; off > 0; off >>= 1) {
    if (t < off) { r0[t] = max(r0[t], r0[t + off]); r1[t] = max(r1[t], r1[t + off]); }
    __syncthreads();
  }
  if (t == 0) { atomicMax(&mm[0], r0[0]); atomicMax(&mm[1], r1[0]); }
}

// ---------- 2) bucket aggregates: count + sum of exp(s - smax) ----------

__global__ void hist_kernel(const u32* __restrict__ keyRaw, const u32* __restrict__ mm,
                            u32* __restrict__ hist, float* __restrict__ sumExp) {
  int i = blockIdx.x * 256 + threadIdx.x;
  u32 key = keyRaw[i];
  u32 kmin = ~mm[0], kmax = mm[1];
  u32 g = bucket_of(key, kmin, kmax);
  float smax = key_to_score(kmin);
  float s = key_to_score(key);
  atomicAdd(&hist[g], 1u);
  atomicAdd(&sumExp[g], fexp(s - smax));
}

// ---------- 3) single-pass exclusive scan (decoupled lookback) ----------

__global__ __launch_bounds__(256) void scan_kernel(u32* __restrict__ hist,
                                                   u64* __restrict__ flags,
                                                   u32* __restrict__ cstart) {
  __shared__ u32 sh[256];
  __shared__ u32 exclu;
  int t = threadIdx.x, b = blockIdx.x;
  int i = b * 256 + t;
  u32 v = hist[i];
  sh[t] = v;
  __syncthreads();
  for (int off = 1; off < 256; off <<= 1) {
    u32 x2 = (t >= off) ? sh[t - off] : 0u;
    __syncthreads();
    sh[t] += x2;
    __syncthreads();
  }
  if (t == 0) {
    u32 agg = sh[255];
    if (b == 0) {
      atomicExch(&flags[0], (2ull << 32) | (u64)agg);
      exclu = 0u;
    } else {
      atomicExch(&flags[b], (1ull << 32) | (u64)agg);
      u32 ex = 0; int j = b - 1;
      for (;;) {
        u64 f = atomicAdd(&flags[j], 0ull);     // device-scope load
        u32 st = (u32)(f >> 32);
        if (st == 0u) continue;                 // spin: 512 blocks all co-resident
        ex += (u32)f;
        if (st == 2u) break;
        --j;
      }
      atomicExch(&flags[b], (2ull << 32) | (u64)(ex + agg));
      exclu = ex;
    }
  }
  __syncthreads();
  u32 e = sh[t] - v + exclu;                    // exclusive global prefix = cdf
  hist[i] = e;
  if ((i & 63) == 0) cstart[i >> 6] = e;        // chunk element starts
  if (i == 0) { cstart[NCHUNKS] = N_ITEMS; hist[NB] = N_ITEMS; }
}

// ---------- 4) PAV over buckets, linear domain ----------
// Record: ST = element start position, SY = sum exp(s - smax) over block.
// Records tile [0,N) contiguously; ends implicit. val_a<=val_b <=> SY_a*SW_b <= SY_b*SW_a.

__global__ __launch_bounds__(64) void pav_chunk_kernel(const u32* __restrict__ cdf,
                                                       const float* __restrict__ sumExp,
                                                       float* __restrict__ SY,
                                                       int* __restrict__ ST,
                                                       int* __restrict__ cnt) {
  __shared__ u32 cdf_s[65][64];   // [bucket-in-chunk][chunk lane]; rows <k reused as ST stack
  __shared__ float sum_s[64][64]; // rows <k reused as SY stack
  int t = threadIdx.x;
  int B0 = blockIdx.x * 4096;     // 64 chunks of 64 buckets per block
  for (int r = 0; r < 64; ++r) {  // coalesced staging
    int g = B0 + r * 64 + t;
    cdf_s[t][r] = cdf[g];
    sum_s[t][r] = sumExp[g];
  }
  cdf_s[64][t] = cdf[B0 + t * 64 + 64];  // chunk end boundary (hist[NB] = N)
  __syncthreads();
  int ptr = 0; bool have = false;
  float syT = 0.0f; int stT = 0;
  for (int k = 0; k < 64; ++k) {
    u32 cs = cdf_s[k][t], ce = cdf_s[k + 1][t];
    if (ce == cs) continue;                 // empty bucket
    float syC = sum_s[k][t];
    int stC = (int)cs, eC = (int)ce - 1;
    while (have) {
      float SWc = wsumf(stC, eC);
      float SWt = wsumf(stT, stC - 1);
      if (!(syT * SWc <= syC * SWt)) break; // merge while val_top <= val_cur
      syC += syT; stC = stT;
      if (ptr == 0) { have = false; break; }
      --ptr;
      stT = (int)cdf_s[ptr][t]; syT = sum_s[ptr][t];
    }
    if (have) { cdf_s[ptr][t] = (u32)stT; sum_s[ptr][t] = syT; ++ptr; } // push (idx < k: safe reuse)
    stT = stC; syT = syC; have = true;
  }
  int slotBase = (blockIdx.x * 64 + t) * 64;
  for (int k2 = 0; k2 < ptr; ++k2) {
    ST[slotBase + k2] = (int)cdf_s[k2][t];
    SY[slotBase + k2] = sum_s[k2][t];
  }
  int n = ptr;
  if (have) { ST[slotBase + n] = stT; SY[slotBase + n] = syT; ++n; }
  cnt[blockIdx.x * 64 + t] = n;
}

// ---------- 5) multi-level tree merge ----------

__global__ void merge_multi_kernel(float* __restrict__ SY, int* __restrict__ ST,
                                   int* __restrict__ cnt, const u32* __restrict__ cstart,
                                   int l0, int L) {
  __shared__ int lcnt[16];
  __shared__ int ca[8], cb[8], cM[8];
  int t = threadIdx.x;
  int G = 1 << L;                  // incoming groups per block
  int SC = 1 << l0;                // chunks per incoming group
  int baseC = blockIdx.x * G * SC;
  if (t < G) lcnt[t] = cnt[baseC + t * SC];
  __syncthreads();
  for (int j = 0; j < L; ++j) {
    int P = G >> (j + 1);
    if (t < P) {
      int p = t;
      int kL = p << (j + 1), kR = kL + (1 << j);
      int slotL = (baseC + kL * SC) * 64, slotR = (baseC + kR * SC) * 64;
      int nL = lcnt[kL], nR = lcnt[kR];
      int a = 0, b = 0, hasM = 0;
      if (nL > 0 && nR > 0) {
        int gstartR = (int)cstart[baseC + kR * SC];
        int gendR   = (int)cstart[baseC + (kR + (1 << j)) * SC];
        float SYL = SY[slotL + nL - 1]; int stL = ST[slotL + nL - 1];
        float SYR = SY[slotR];
        int eR = (nR > 1) ? (ST[slotR + 1] - 1) : (gendR - 1);
        float SWL = wsumf(stL, gstartR - 1);
        float SWR = wsumf(gstartR, eR);
        if (SYL * SWR <= SYR * SWL) {
          hasM = 1;
          float SYM = SYL + SYR; int Ms = stL, Me = eR;
          a = 1; b = 1;
          for (;;) {
            float SWM = wsumf(Ms, Me);
            if (a < nL) {
              float SYe = SY[slotL + nL - 1 - a]; int ste = ST[slotL + nL - 1 - a];
              float SWe = wsumf(ste, Ms - 1);
              if (SYe * SWM <= SYM * SWe) { SYM += SYe; Ms = ste; ++a; continue; }
            }
            if (b < nR) {
              float SYb = SY[slotR + b]; int sb = ST[slotR + b];
              int eb = (b + 1 < nR) ? (ST[slotR + b + 1] - 1) : (gendR - 1);
              float SWb = wsumf(sb, eb);
              if (SYM * SWb <= SYb * SWM) { SYM += SYb; Me = eb; ++b; continue; }
            }
            break;
          }
          SY[slotL + nL - a] = SYM; ST[slotL + nL - a] = Ms; // below copy dest, never clobbered
        }
      }
      ca[p] = a; cb[p] = b; cM[p] = hasM;
    }
    __syncthreads();
    // staged compaction copies (dest <= src)
    for (int p = 0; p < P; ++p) {
      int kL = p << (j + 1), kR = kL + (1 << j);
      int nL = lcnt[kL], nR = lcnt[kR];
      int a = ca[p], b = cb[p], hasM = cM[p];
      int slotL = (baseC + kL * SC) * 64, slotR = (baseC + kR * SC) * 64;
      int destBase = slotL + nL - a + hasM;
      int srcBase = slotR + b;
      int ncopy = nR - b;
      for (int off = 0; off < ncopy; off += blockDim.x) {
        int k2 = off + t; bool act = k2 < ncopy;
        float vs = 0.f; int vt = 0;
        if (act) { vs = SY[srcBase + k2]; vt = ST[srcBase + k2]; }
        __syncthreads();
        if (act) { SY[destBase + k2] = vs; ST[destBase + k2] = vt; }
        __syncthreads();
      }
    }
    __syncthreads();
    if (t < P) {
      int p = t; int kL = p << (j + 1), kR = kL + (1 << j);
      lcnt[kL] = lcnt[kL] - ca[p] + cM[p] + (lcnt[kR] - cb[p]);
    }
    __syncthreads();
  }
  if (t == 0) cnt[baseC] = lcnt[0];
}

// ---------- 6) ranks + transform, fully coalesced output ----------

__global__ void out_kernel(const u32* __restrict__ keyRaw, const u32* __restrict__ mm,
                           const u32* __restrict__ cdf,
                           const float* __restrict__ SY, const int* __restrict__ ST,
                           const int* __restrict__ cnt, float* __restrict__ out) {
  int i = blockIdx.x * 256 + threadIdx.x;
  u32 key = keyRaw[i];
  u32 kmin = ~mm[0], kmax = mm[1];
  float smax = key_to_score(kmin);
  u32 g = bucket_of(key, kmin, kmax);
  int p = (int)cdf[g];               // block is bucket-aligned: position of bucket start
  int m = cnt[0];
  int lo = 0, hi = m - 1;
  while (lo < hi) {
    int mid = (lo + hi + 1) >> 1;
    if (ST[mid] <= p) lo = mid; else hi = mid - 1;
  }
  int s0 = ST[lo];
  int e0 = (lo + 1 < m) ? (ST[lo + 1] - 1) : (N_ITEMS - 1);
  float SW = wsumf(s0, e0);
  float s = key_to_score(key);
  float rank = fexp(s - smax) * SW / SY[lo];
  out[i] = floorf(rank * (1.0f / 3.0f)) + 1.0f;
}

// ---------- launch ----------

extern "C" void kernel_launch(void* const* d_in, const int* in_sizes, int n_in,
                              void* d_out, int out_size, void* d_ws, size_t ws_size,
                              hipStream_t stream) {
  const float* x  = (const float*)d_in[0];
  const float* w1 = (const float*)d_in[1];
  const float* b1 = (const float*)d_in[2];
  const float* w2 = (const float*)d_in[3];
  const float* b2 = (const float*)d_in[4];
  float* out = (float*)d_out;

  char* ws = (char*)d_ws;
  size_t o = 0;
  u32* mm     = (u32*)(ws + o); o += 16;
  u32* hist   = (u32*)(ws + o); o += (size_t)(NB + 4) * 4;       // NB+1 used
  float* sumExp = (float*)(ws + o); o += (size_t)NB * 4;
  u64* flags  = (u64*)(ws + o); o += (size_t)SCAN_BLOCKS * 8;
  u32* cstart = (u32*)(ws + o); o += (size_t)(NCHUNKS + 4) * 4;  // NCHUNKS+1 used
  u32* keyRaw = (u32*)(ws + o); o += (size_t)N_ITEMS * 4;
  float* SY   = (float*)(ws + o); o += (size_t)N_ITEMS * 4;
  int* ST     = (int*)(ws + o);   o += (size_t)N_ITEMS * 4;
  int* cnt    = (int*)(ws + o);   o += (size_t)NCHUNKS * 4;

  hipMemsetAsync(mm, 0, 16, stream);  // only mm needs pre-kernel zero

  score_key_kernel<<<N_ITEMS / 256, 256, 0, stream>>>(x, w1, b1, w2, b2,
                                                      keyRaw, mm, hist, sumExp, flags);
  hist_kernel<<<N_ITEMS / 256, 256, 0, stream>>>(keyRaw, mm, hist, sumExp);
  scan_kernel<<<SCAN_BLOCKS, 256, 0, stream>>>(hist, flags, cstart);
  pav_chunk_kernel<<<NCHUNKS / 64, 64, 0, stream>>>(hist, sumExp, SY, ST, cnt);
  // 11 tree levels in 3 launches: 0-3, 4-7, 8-10
  merge_multi_kernel<<<NCHUNKS / 16, 256, 0, stream>>>(SY, ST, cnt, cstart, 0, 4);
  merge_multi_kernel<<<NCHUNKS / 256, 256, 0, stream>>>(SY, ST, cnt, cstart, 4, 4);
  merge_multi_kernel<<<1, 256, 0, stream>>>(SY, ST, cnt, cstart, 8, 3);
  out_kernel<<<N_ITEMS / 256, 256, 0, stream>>>(keyRaw, mm, hist, SY, ST, cnt, out);
}

// Round 5
// 149.970 us; speedup vs baseline: 2.4691x; 1.1729x over previous
//
#include <hip/hip_runtime.h>
#include <stdint.h>

typedef unsigned int u32;
typedef unsigned long long u64;

#define N_ITEMS 131072
#define NB 131072                   // buckets (monotone in descending score)
#define NSLICE 8                    // XCD-sliced histogram copies
#define CHUNK 64
#define NCHUNKS 2048                // NB / CHUNK
#define SCAN_BLOCKS 512             // NB / 256
#define FIXSCALE 268435456.0f       // 2^28 fixed-point scale for sum(exp)
#define FIXMASK ((1ull << 46) - 1)

// ---------- helpers ----------

// sum_{i=s}^{e} (N - i) — exact weight-side sum of exp(w) over sorted positions
__device__ __forceinline__ float wsumf(int s, int e) {
  return 0.5f * (float)(e - s + 1) * (float)(2 * N_ITEMS - s - e);
}

__device__ __forceinline__ float key_to_score(u32 key) {
  u32 m = ~key;
  u32 u = (m & 0x80000000u) ? (m ^ 0x80000000u) : ~m;
  return __uint_as_float(u);
}

#define LOG2E 1.4426950408889634f
__device__ __forceinline__ float fexp(float x) { return exp2f(x * LOG2E); }

// ascending key == descending score; ascending bucket == descending score
__device__ __forceinline__ u32 bucket_of(u32 key, u32 kmin, u32 kmax) {
  double scale = (double)NB / ((double)(kmax - kmin) + 1.0);
  u32 b = (u32)((double)(key - kmin) * scale);
  return b < NB ? b : (NB - 1);
}

// ---------- 1) scores -> keys, min/max, flags zeroing ----------

__global__ void score_key_kernel(const float* __restrict__ x,
                                 const float* __restrict__ w1,
                                 const float* __restrict__ b1,
                                 const float* __restrict__ w2,
                                 const float* __restrict__ b2,
                                 u32* __restrict__ keyRaw, u32* __restrict__ mm,
                                 u64* __restrict__ flags) {
  __shared__ u32 r0[256], r1[256];
  int t = threadIdx.x;
  int i = blockIdx.x * 256 + t;
  float xv = x[i];
  float s = b2[0];
#pragma unroll
  for (int j = 0; j < 32; ++j) {
    float h = fmaf(xv, w1[j], b1[j]);
    h = fmaxf(h, 0.0f);
    s = fmaf(h, w2[j], s);
  }
  u32 u = __float_as_uint(s);
  u32 m = u ^ ((u & 0x80000000u) ? 0xFFFFFFFFu : 0x80000000u); // ascending map
  u32 key = ~m;
  keyRaw[i] = key;
  if (i < SCAN_BLOCKS) flags[i] = 0ull;
  // min/max via two atomicMax on zero-initialized slots: mm[0]=max(~key), mm[1]=max(key)
  r0[t] = ~key; r1[t] = key;
  __syncthreads();
  for (int off = 128; off > 0; off >>= 1) {
    if (t < off) { r0[t] = max(r0[t], r0[t + off]); r1[t] = max(r1[t], r1[t + off]); }
    __syncthreads();
  }
  if (t == 0) { atomicMax(&mm[0], r0[0]); atomicMax(&mm[1], r1[0]); }
}

// ---------- 2) bucket aggregates: ONE packed u64 atomic per item, XCD-sliced ----------
// bits [46:63] = count, bits [0:45] = fixed-point (2^28) sum of exp(s - smax)

__global__ void hist_kernel(const u32* __restrict__ keyRaw, const u32* __restrict__ mm,
                            u64* __restrict__ hist8) {
  int i = blockIdx.x * 256 + threadIdx.x;
  u32 key = keyRaw[i];
  u32 kmin = ~mm[0], kmax = mm[1];
  u32 g = bucket_of(key, kmin, kmax);
  float smax = key_to_score(kmin);
  float v = fexp(key_to_score(key) - smax);           // in (0, 1]
  u64 fix = (u64)fmaxf(1.0f, fmaf(v, FIXSCALE, 0.5f)); // clamp: SY can never be 0
  size_t slice = (size_t)(blockIdx.x & (NSLICE - 1)) * NB;
  atomicAdd(&hist8[slice + g], (1ull << 46) | fix);
}

// ---------- 3) 8-way reduce + single-pass exclusive scan (decoupled lookback) ----------

__global__ __launch_bounds__(256) void scan_kernel(const u64* __restrict__ hist8,
                                                   u64* __restrict__ flags,
                                                   u32* __restrict__ cdf,
                                                   float* __restrict__ sumExp,
                                                   u32* __restrict__ cstart) {
  __shared__ u32 sh[256];
  __shared__ u32 exclu;
  int t = threadIdx.x, b = blockIdx.x;
  int i = b * 256 + t;
  u64 acc = 0;
#pragma unroll
  for (int c = 0; c < NSLICE; ++c) acc += hist8[(size_t)c * NB + i];
  u32 v = (u32)(acc >> 46);
  sumExp[i] = (float)(acc & FIXMASK) * (1.0f / FIXSCALE);
  sh[t] = v;
  __syncthreads();
  for (int off = 1; off < 256; off <<= 1) {
    u32 x2 = (t >= off) ? sh[t - off] : 0u;
    __syncthreads();
    sh[t] += x2;
    __syncthreads();
  }
  if (t == 0) {
    u32 agg = sh[255];
    if (b == 0) {
      atomicExch(&flags[0], (2ull << 32) | (u64)agg);
      exclu = 0u;
    } else {
      atomicExch(&flags[b], (1ull << 32) | (u64)agg);
      u32 ex = 0; int j = b - 1;
      for (;;) {
        u64 f = atomicAdd(&flags[j], 0ull);     // device-scope load
        u32 st = (u32)(f >> 32);
        if (st == 0u) continue;                 // spin: 512 blocks all co-resident
        ex += (u32)f;
        if (st == 2u) break;
        --j;
      }
      atomicExch(&flags[b], (2ull << 32) | (u64)(ex + agg));
      exclu = ex;
    }
  }
  __syncthreads();
  u32 e = sh[t] - v + exclu;                    // exclusive global prefix = cdf
  cdf[i] = e;
  if ((i & 63) == 0) cstart[i >> 6] = e;        // chunk element starts
  if (i == 0) { cstart[NCHUNKS] = N_ITEMS; cdf[NB] = N_ITEMS; }
}

// ---------- 4) PAV over buckets, linear domain ----------
// Record: ST = element start position, SY = sum exp(s - smax) over block.
// Records tile [0,N) contiguously; ends implicit. val_a<=val_b <=> SY_a*SW_b <= SY_b*SW_a.

__global__ __launch_bounds__(64) void pav_chunk_kernel(const u32* __restrict__ cdf,
                                                       const float* __restrict__ sumExp,
                                                       float* __restrict__ SY,
                                                       int* __restrict__ ST,
                                                       int* __restrict__ cnt) {
  __shared__ u32 cdf_s[65][64];   // [bucket-in-chunk][chunk lane]; rows <k reused as ST stack
  __shared__ float sum_s[64][64]; // rows <k reused as SY stack
  int t = threadIdx.x;
  int B0 = blockIdx.x * 4096;     // 64 chunks of 64 buckets per block
  for (int r = 0; r < 64; ++r) {  // coalesced staging
    int g = B0 + r * 64 + t;
    cdf_s[t][r] = cdf[g];
    sum_s[t][r] = sumExp[g];
  }
  cdf_s[64][t] = cdf[B0 + t * 64 + 64];  // chunk end boundary (cdf[NB] = N)
  __syncthreads();
  int ptr = 0; bool have = false;
  float syT = 0.0f; int stT = 0;
  for (int k = 0; k < 64; ++k) {
    u32 cs = cdf_s[k][t], ce = cdf_s[k + 1][t];
    if (ce == cs) continue;                 // empty bucket
    float syC = sum_s[k][t];
    int stC = (int)cs, eC = (int)ce - 1;
    while (have) {
      float SWc = wsumf(stC, eC);
      float SWt = wsumf(stT, stC - 1);
      if (!(syT * SWc <= syC * SWt)) break; // merge while val_top <= val_cur
      syC += syT; stC = stT;
      if (ptr == 0) { have = false; break; }
      --ptr;
      stT = (int)cdf_s[ptr][t]; syT = sum_s[ptr][t];
    }
    if (have) { cdf_s[ptr][t] = (u32)stT; sum_s[ptr][t] = syT; ++ptr; } // push (idx < k: safe reuse)
    stT = stC; syT = syC; have = true;
  }
  int slotBase = (blockIdx.x * 64 + t) * 64;
  for (int k2 = 0; k2 < ptr; ++k2) {
    ST[slotBase + k2] = (int)cdf_s[k2][t];
    SY[slotBase + k2] = sum_s[k2][t];
  }
  int n = ptr;
  if (have) { ST[slotBase + n] = stT; SY[slotBase + n] = syT; ++n; }
  cnt[blockIdx.x * 64 + t] = n;
}

// ---------- 5) multi-level tree merge ----------

__global__ void merge_multi_kernel(float* __restrict__ SY, int* __restrict__ ST,
                                   int* __restrict__ cnt, const u32* __restrict__ cstart,
                                   int l0, int L) {
  __shared__ int lcnt[16];
  __shared__ int ca[8], cb[8], cM[8];
  int t = threadIdx.x;
  int G = 1 << L;                  // incoming groups per block
  int SC = 1 << l0;                // chunks per incoming group
  int baseC = blockIdx.x * G * SC;
  if (t < G) lcnt[t] = cnt[baseC + t * SC];
  __syncthreads();
  for (int j = 0; j < L; ++j) {
    int P = G >> (j + 1);
    if (t < P) {
      int p = t;
      int kL = p << (j + 1), kR = kL + (1 << j);
      int slotL = (baseC + kL * SC) * 64, slotR = (baseC + kR * SC) * 64;
      int nL = lcnt[kL], nR = lcnt[kR];
      int a = 0, b = 0, hasM = 0;
      if (nL > 0 && nR > 0) {
        int gstartR = (int)cstart[baseC + kR * SC];
        int gendR   = (int)cstart[baseC + (kR + (1 << j)) * SC];
        float SYL = SY[slotL + nL - 1]; int stL = ST[slotL + nL - 1];
        float SYR = SY[slotR];
        int eR = (nR > 1) ? (ST[slotR + 1] - 1) : (gendR - 1);
        float SWL = wsumf(stL, gstartR - 1);
        float SWR = wsumf(gstartR, eR);
        if (SYL * SWR <= SYR * SWL) {
          hasM = 1;
          float SYM = SYL + SYR; int Ms = stL, Me = eR;
          a = 1; b = 1;
          for (;;) {
            float SWM = wsumf(Ms, Me);
            if (a < nL) {
              float SYe = SY[slotL + nL - 1 - a]; int ste = ST[slotL + nL - 1 - a];
              float SWe = wsumf(ste, Ms - 1);
              if (SYe * SWM <= SYM * SWe) { SYM += SYe; Ms = ste; ++a; continue; }
            }
            if (b < nR) {
              float SYb = SY[slotR + b]; int sb = ST[slotR + b];
              int eb = (b + 1 < nR) ? (ST[slotR + b + 1] - 1) : (gendR - 1);
              float SWb = wsumf(sb, eb);
              if (SYM * SWb <= SYb * SWM) { SYM += SYb; Me = eb; ++b; continue; }
            }
            break;
          }
          SY[slotL + nL - a] = SYM; ST[slotL + nL - a] = Ms; // below copy dest, never clobbered
        }
      }
      ca[p] = a; cb[p] = b; cM[p] = hasM;
    }
    __syncthreads();
    // staged compaction copies (dest <= src)
    for (int p = 0; p < P; ++p) {
      int kL = p << (j + 1), kR = kL + (1 << j);
      int nL = lcnt[kL], nR = lcnt[kR];
      int a = ca[p], b = cb[p], hasM = cM[p];
      int slotL = (baseC + kL * SC) * 64, slotR = (baseC + kR * SC) * 64;
      int destBase = slotL + nL - a + hasM;
      int srcBase = slotR + b;
      int ncopy = nR - b;
      for (int off = 0; off < ncopy; off += blockDim.x) {
        int k2 = off + t; bool act = k2 < ncopy;
        float vs = 0.f; int vt = 0;
        if (act) { vs = SY[srcBase + k2]; vt = ST[srcBase + k2]; }
        __syncthreads();
        if (act) { SY[destBase + k2] = vs; ST[destBase + k2] = vt; }
        __syncthreads();
      }
    }
    __syncthreads();
    if (t < P) {
      int p = t; int kL = p << (j + 1), kR = kL + (1 << j);
      lcnt[kL] = lcnt[kL] - ca[p] + cM[p] + (lcnt[kR] - cb[p]);
    }
    __syncthreads();
  }
  if (t == 0) cnt[baseC] = lcnt[0];
}

// ---------- 6) ranks + transform, fully coalesced output ----------

__global__ void out_kernel(const u32* __restrict__ keyRaw, const u32* __restrict__ mm,
                           const u32* __restrict__ cdf,
                           const float* __restrict__ SY, const int* __restrict__ ST,
                           const int* __restrict__ cnt, float* __restrict__ out) {
  int i = blockIdx.x * 256 + threadIdx.x;
  u32 key = keyRaw[i];
  u32 kmin = ~mm[0], kmax = mm[1];
  float smax = key_to_score(kmin);
  u32 g = bucket_of(key, kmin, kmax);
  int p = (int)cdf[g];               // block is bucket-aligned: position of bucket start
  int m = cnt[0];
  int lo = 0, hi = m - 1;
  while (lo < hi) {
    int mid = (lo + hi + 1) >> 1;
    if (ST[mid] <= p) lo = mid; else hi = mid - 1;
  }
  int s0 = ST[lo];
  int e0 = (lo + 1 < m) ? (ST[lo + 1] - 1) : (N_ITEMS - 1);
  float SW = wsumf(s0, e0);
  float s = key_to_score(key);
  float rank = fexp(s - smax) * SW / SY[lo];
  out[i] = floorf(rank * (1.0f / 3.0f)) + 1.0f;
}

// ---------- launch ----------

extern "C" void kernel_launch(void* const* d_in, const int* in_sizes, int n_in,
                              void* d_out, int out_size, void* d_ws, size_t ws_size,
                              hipStream_t stream) {
  const float* x  = (const float*)d_in[0];
  const float* w1 = (const float*)d_in[1];
  const float* b1 = (const float*)d_in[2];
  const float* w2 = (const float*)d_in[3];
  const float* b2 = (const float*)d_in[4];
  float* out = (float*)d_out;

  char* ws = (char*)d_ws;
  size_t o = 0;
  u32* mm     = (u32*)(ws + o); o += 16;
  u64* hist8  = (u64*)(ws + o); o += (size_t)NSLICE * NB * 8;    // 8 MB, XCD-sliced
  u64* flags  = (u64*)(ws + o); o += (size_t)SCAN_BLOCKS * 8;
  u32* cdf    = (u32*)(ws + o); o += (size_t)(NB + 4) * 4;       // NB+1 used
  float* sumExp = (float*)(ws + o); o += (size_t)NB * 4;
  u32* cstart = (u32*)(ws + o); o += (size_t)(NCHUNKS + 4) * 4;  // NCHUNKS+1 used
  u32* keyRaw = (u32*)(ws + o); o += (size_t)N_ITEMS * 4;
  float* SY   = (float*)(ws + o); o += (size_t)N_ITEMS * 4;
  int* ST     = (int*)(ws + o);   o += (size_t)N_ITEMS * 4;
  int* cnt    = (int*)(ws + o);   o += (size_t)NCHUNKS * 4;

  hipMemsetAsync(mm, 0, 16, stream);
  hipMemsetAsync(hist8, 0, (size_t)NSLICE * NB * 8, stream);

  score_key_kernel<<<N_ITEMS / 256, 256, 0, stream>>>(x, w1, b1, w2, b2,
                                                      keyRaw, mm, flags);
  hist_kernel<<<N_ITEMS / 256, 256, 0, stream>>>(keyRaw, mm, hist8);
  scan_kernel<<<SCAN_BLOCKS, 256, 0, stream>>>(hist8, flags, cdf, sumExp, cstart);
  pav_chunk_kernel<<<NCHUNKS / 64, 64, 0, stream>>>(cdf, sumExp, SY, ST, cnt);
  // 11 tree levels in 3 launches: 0-3, 4-7, 8-10
  merge_multi_kernel<<<NCHUNKS / 16, 256, 0, stream>>>(SY, ST, cnt, cstart, 0, 4);
  merge_multi_kernel<<<NCHUNKS / 256, 256, 0, stream>>>(SY, ST, cnt, cstart, 4, 4);
  merge_multi_kernel<<<1, 256, 0, stream>>>(SY, ST, cnt, cstart, 8, 3);
  out_kernel<<<N_ITEMS / 256, 256, 0, stream>>>(keyRaw, mm, cdf, SY, ST, cnt, out);
}

// Round 6
// 134.410 us; speedup vs baseline: 2.7550x; 1.1158x over previous
//
#include <hip/hip_runtime.h>
#include <stdint.h>

typedef unsigned int u32;
typedef unsigned long long u64;

#define N_ITEMS 131072
#define NB 131072                   // buckets (monotone in descending score)
#define NSLICE 8                    // XCD-sliced histogram copies
#define CHUNK 64
#define NCHUNKS 2048                // NB / CHUNK
#define SCAN_BLOCKS 512             // NB / 256
#define FIXSCALE 268435456.0f       // 2^28 fixed-point scale for sum(exp)
#define FIXMASK ((1ull << 46) - 1)

// ---------- helpers ----------

// sum_{i=s}^{e} (N - i) — exact weight-side sum of exp(w) over sorted positions
__device__ __forceinline__ float wsumf(int s, int e) {
  return 0.5f * (float)(e - s + 1) * (float)(2 * N_ITEMS - s - e);
}

__device__ __forceinline__ float key_to_score(u32 key) {
  u32 m = ~key;
  u32 u = (m & 0x80000000u) ? (m ^ 0x80000000u) : ~m;
  return __uint_as_float(u);
}

#define LOG2E 1.4426950408889634f
__device__ __forceinline__ float fexp(float x) { return exp2f(x * LOG2E); }

// ascending key == descending score; ascending bucket == descending score
__device__ __forceinline__ u32 bucket_of(u32 key, u32 kmin, u32 kmax) {
  double scale = (double)NB / ((double)(kmax - kmin) + 1.0);
  u32 b = (u32)((double)(key - kmin) * scale);
  return b < NB ? b : (NB - 1);
}

// ---------- 1) scores -> keys, per-block minmax partials, all buffer zeroing ----------

__global__ void score_key_kernel(const float* __restrict__ x,
                                 const float* __restrict__ w1,
                                 const float* __restrict__ b1,
                                 const float* __restrict__ w2,
                                 const float* __restrict__ b2,
                                 u32* __restrict__ keyRaw,
                                 u32* __restrict__ pmin, u32* __restrict__ pmax,
                                 u64* __restrict__ hist8, u64* __restrict__ flags) {
  __shared__ u32 r0[256], r1[256];
  int t = threadIdx.x;
  int i = blockIdx.x * 256 + t;
  // cooperative zero of the sliced histogram (fully coalesced per slice)
#pragma unroll
  for (int k = 0; k < NSLICE; ++k) hist8[(size_t)k * NB + i] = 0ull;
  if (i < SCAN_BLOCKS) flags[i] = 0ull;
  float xv = x[i];
  float s = b2[0];
#pragma unroll
  for (int j = 0; j < 32; ++j) {
    float h = fmaf(xv, w1[j], b1[j]);
    h = fmaxf(h, 0.0f);
    s = fmaf(h, w2[j], s);
  }
  u32 u = __float_as_uint(s);
  u32 m = u ^ ((u & 0x80000000u) ? 0xFFFFFFFFu : 0x80000000u); // ascending map
  u32 key = ~m;
  keyRaw[i] = key;
  r0[t] = key; r1[t] = key;
  __syncthreads();
  for (int off = 128; off > 0; off >>= 1) {
    if (t < off) { r0[t] = min(r0[t], r0[t + off]); r1[t] = max(r1[t], r1[t + off]); }
    __syncthreads();
  }
  if (t == 0) { pmin[blockIdx.x] = r0[0]; pmax[blockIdx.x] = r1[0]; }
}

// ---------- 2) bucket aggregates: ONE packed u64 atomic per item, XCD-sliced ----------
// bits [46:63] = count, bits [0:45] = fixed-point (2^28) sum of exp(s - smax)

__global__ void hist_kernel(const u32* __restrict__ keyRaw,
                            const u32* __restrict__ pmin, const u32* __restrict__ pmax,
                            u64* __restrict__ hist8, u32* __restrict__ mm) {
  __shared__ u32 s0[256], s1[256];
  int t = threadIdx.x;
  s0[t] = min(pmin[t], pmin[t + 256]);
  s1[t] = max(pmax[t], pmax[t + 256]);
  __syncthreads();
  for (int off = 128; off > 0; off >>= 1) {
    if (t < off) { s0[t] = min(s0[t], s0[t + off]); s1[t] = max(s1[t], s1[t + off]); }
    __syncthreads();
  }
  u32 kmin = s0[0], kmax = s1[0];
  if (blockIdx.x == 0 && t == 0) { mm[0] = kmin; mm[1] = kmax; }  // for out_kernel
  int i = blockIdx.x * 256 + t;
  u32 key = keyRaw[i];
  u32 g = bucket_of(key, kmin, kmax);
  float smax = key_to_score(kmin);
  float v = fexp(key_to_score(key) - smax);            // in (0, 1]
  u64 fix = (u64)fmaxf(1.0f, fmaf(v, FIXSCALE, 0.5f)); // clamp: SY can never be 0
  size_t slice = (size_t)(blockIdx.x & (NSLICE - 1)) * NB;
  atomicAdd(&hist8[slice + g], (1ull << 46) | fix);
}

// ---------- 3) fused: 8-way reduce + lookback scan + per-chunk PAV from LDS ----------
// A scan block owns 256 buckets = 4 chunks; its inclusive aggregate is the chunk-end
// boundary, so PAV for those chunks needs nothing beyond block-local data.

__global__ __launch_bounds__(256) void scan_pav_kernel(const u64* __restrict__ hist8,
                                                       u64* __restrict__ flags,
                                                       u32* __restrict__ cdf,
                                                       u32* __restrict__ cstart,
                                                       float* __restrict__ SY,
                                                       int* __restrict__ ST,
                                                       int* __restrict__ cnt) {
  __shared__ u32 sh[256];
  __shared__ float seL[256];
  __shared__ u32 cdfL[257];
  __shared__ u32 exclu_s;
  __shared__ u32 stkST[64][4];
  __shared__ float stkSY[64][4];
  int t = threadIdx.x, b = blockIdx.x;
  int i = b * 256 + t;
  u64 acc = 0;
#pragma unroll
  for (int c = 0; c < NSLICE; ++c) acc += hist8[(size_t)c * NB + i];
  u32 v = (u32)(acc >> 46);
  seL[t] = (float)(acc & FIXMASK) * (1.0f / FIXSCALE);
  sh[t] = v;
  __syncthreads();
  for (int off = 1; off < 256; off <<= 1) {
    u32 x2 = (t >= off) ? sh[t - off] : 0u;
    __syncthreads();
    sh[t] += x2;
    __syncthreads();
  }
  if (t == 0) {
    u32 agg = sh[255];
    if (b == 0) {
      atomicExch(&flags[0], (2ull << 32) | (u64)agg);
      exclu_s = 0u;
    } else {
      atomicExch(&flags[b], (1ull << 32) | (u64)agg);
      u32 ex = 0; int j = b - 1;
      for (;;) {
        u64 f = atomicAdd(&flags[j], 0ull);     // device-scope load
        u32 st = (u32)(f >> 32);
        if (st == 0u) continue;                 // spin: 512 blocks all co-resident
        ex += (u32)f;
        if (st == 2u) break;
        --j;
      }
      atomicExch(&flags[b], (2ull << 32) | (u64)(ex + agg));
      exclu_s = ex;
    }
  }
  __syncthreads();
  u32 exclu = exclu_s;
  u32 e = sh[t] - v + exclu;                    // exclusive global prefix = cdf
  cdfL[t] = e;
  if (t == 255) cdfL[256] = exclu + sh[255];    // block-end boundary
  cdf[i] = e;
  if ((t & 63) == 0) cstart[i >> 6] = e;        // chunk element starts
  if (i == 0) cstart[NCHUNKS] = N_ITEMS;
  __syncthreads();
  // PAV for this block's 4 chunks, entirely from LDS
  if (t < 4) {
    int c = b * 4 + t;
    int ptr = 0; bool have = false;
    float syT = 0.0f; int stT = 0;
    for (int k = 0; k < 64; ++k) {
      u32 cs = cdfL[t * 64 + k], ce = cdfL[t * 64 + k + 1];
      if (ce == cs) continue;                 // empty bucket
      float syC = seL[t * 64 + k];
      int stC = (int)cs, eC = (int)ce - 1;
      while (have) {
        float SWc = wsumf(stC, eC);
        float SWt = wsumf(stT, stC - 1);
        if (!(syT * SWc <= syC * SWt)) break; // merge while val_top <= val_cur
        syC += syT; stC = stT;
        if (ptr == 0) { have = false; break; }
        --ptr;
        stT = (int)stkST[ptr][t]; syT = stkSY[ptr][t];
      }
      if (have) { stkST[ptr][t] = (u32)stT; stkSY[ptr][t] = syT; ++ptr; }
      stT = stC; syT = syC; have = true;
    }
    int slotBase = c * 64;
    for (int k2 = 0; k2 < ptr; ++k2) {
      ST[slotBase + k2] = (int)stkST[k2][t];
      SY[slotBase + k2] = stkSY[k2][t];
    }
    int n = ptr;
    if (have) { ST[slotBase + n] = stT; SY[slotBase + n] = syT; ++n; }
    cnt[c] = n;
  }
}

// ---------- 4) multi-level tree merge (levels 0-4 on 64 blocks, 5-10 on 1 block) ----------

__global__ void merge_multi_kernel(float* __restrict__ SY, int* __restrict__ ST,
                                   int* __restrict__ cnt, const u32* __restrict__ cstart,
                                   int l0, int L) {
  __shared__ int lcnt[64];
  __shared__ int ca[32], cb[32], cM[32];
  int t = threadIdx.x;
  int G = 1 << L;                  // incoming groups per block
  int SC = 1 << l0;                // chunks per incoming group
  int baseC = blockIdx.x * G * SC;
  if (t < G) lcnt[t] = cnt[baseC + t * SC];
  __syncthreads();
  for (int j = 0; j < L; ++j) {
    int P = G >> (j + 1);
    if (t < P) {
      int p = t;
      int kL = p << (j + 1), kR = kL + (1 << j);
      int slotL = (baseC + kL * SC) * 64, slotR = (baseC + kR * SC) * 64;
      int nL = lcnt[kL], nR = lcnt[kR];
      int a = 0, b = 0, hasM = 0;
      if (nL > 0 && nR > 0) {
        int gstartR = (int)cstart[baseC + kR * SC];
        int gendR   = (int)cstart[baseC + (kR + (1 << j)) * SC];
        float SYL = SY[slotL + nL - 1]; int stL = ST[slotL + nL - 1];
        float SYR = SY[slotR];
        int eR = (nR > 1) ? (ST[slotR + 1] - 1) : (gendR - 1);
        float SWL = wsumf(stL, gstartR - 1);
        float SWR = wsumf(gstartR, eR);
        if (SYL * SWR <= SYR * SWL) {
          hasM = 1;
          float SYM = SYL + SYR; int Ms = stL, Me = eR;
          a = 1; b = 1;
          for (;;) {
            float SWM = wsumf(Ms, Me);
            if (a < nL) {
              float SYe = SY[slotL + nL - 1 - a]; int ste = ST[slotL + nL - 1 - a];
              float SWe = wsumf(ste, Ms - 1);
              if (SYe * SWM <= SYM * SWe) { SYM += SYe; Ms = ste; ++a; continue; }
            }
            if (b < nR) {
              float SYb = SY[slotR + b]; int sb = ST[slotR + b];
              int eb = (b + 1 < nR) ? (ST[slotR + b + 1] - 1) : (gendR - 1);
              float SWb = wsumf(sb, eb);
              if (SYM * SWb <= SYb * SWM) { SYM += SYb; Me = eb; ++b; continue; }
            }
            break;
          }
          SY[slotL + nL - a] = SYM; ST[slotL + nL - a] = Ms; // below copy dest, never clobbered
        }
      }
      ca[p] = a; cb[p] = b; cM[p] = hasM;
    }
    __syncthreads();
    // staged compaction copies (dest <= src)
    for (int p = 0; p < P; ++p) {
      int kL = p << (j + 1), kR = kL + (1 << j);
      int nL = lcnt[kL], nR = lcnt[kR];
      int a = ca[p], b = cb[p], hasM = cM[p];
      int slotL = (baseC + kL * SC) * 64, slotR = (baseC + kR * SC) * 64;
      int destBase = slotL + nL - a + hasM;
      int srcBase = slotR + b;
      int ncopy = nR - b;
      for (int off = 0; off < ncopy; off += blockDim.x) {
        int k2 = off + t; bool act = k2 < ncopy;
        float vs = 0.f; int vt = 0;
        if (act) { vs = SY[srcBase + k2]; vt = ST[srcBase + k2]; }
        __syncthreads();
        if (act) { SY[destBase + k2] = vs; ST[destBase + k2] = vt; }
        __syncthreads();
      }
    }
    __syncthreads();
    if (t < P) {
      int p = t; int kL = p << (j + 1), kR = kL + (1 << j);
      lcnt[kL] = lcnt[kL] - ca[p] + cM[p] + (lcnt[kR] - cb[p]);
    }
    __syncthreads();
  }
  if (t == 0) cnt[baseC] = lcnt[0];
}

// ---------- 5) ranks + transform, fully coalesced output ----------

__global__ void out_kernel(const u32* __restrict__ keyRaw, const u32* __restrict__ mm,
                           const u32* __restrict__ cdf,
                           const float* __restrict__ SY, const int* __restrict__ ST,
                           const int* __restrict__ cnt, float* __restrict__ out) {
  int i = blockIdx.x * 256 + threadIdx.x;
  u32 key = keyRaw[i];
  u32 kmin = mm[0], kmax = mm[1];
  float smax = key_to_score(kmin);
  u32 g = bucket_of(key, kmin, kmax);
  int p = (int)cdf[g];               // block is bucket-aligned: position of bucket start
  int m = cnt[0];
  int lo = 0, hi = m - 1;
  while (lo < hi) {
    int mid = (lo + hi + 1) >> 1;
    if (ST[mid] <= p) lo = mid; else hi = mid - 1;
  }
  int s0 = ST[lo];
  int e0 = (lo + 1 < m) ? (ST[lo + 1] - 1) : (N_ITEMS - 1);
  float SW = wsumf(s0, e0);
  float s = key_to_score(key);
  float rank = fexp(s - smax) * SW / SY[lo];
  out[i] = floorf(rank * (1.0f / 3.0f)) + 1.0f;
}

// ---------- launch ----------

extern "C" void kernel_launch(void* const* d_in, const int* in_sizes, int n_in,
                              void* d_out, int out_size, void* d_ws, size_t ws_size,
                              hipStream_t stream) {
  const float* x  = (const float*)d_in[0];
  const float* w1 = (const float*)d_in[1];
  const float* b1 = (const float*)d_in[2];
  const float* w2 = (const float*)d_in[3];
  const float* b2 = (const float*)d_in[4];
  float* out = (float*)d_out;

  char* ws = (char*)d_ws;
  size_t o = 0;
  u32* mm     = (u32*)(ws + o); o += 16;
  u32* pmin   = (u32*)(ws + o); o += (size_t)SCAN_BLOCKS * 4;
  u32* pmax   = (u32*)(ws + o); o += (size_t)SCAN_BLOCKS * 4;
  u64* hist8  = (u64*)(ws + o); o += (size_t)NSLICE * NB * 8;    // 8 MB, XCD-sliced
  u64* flags  = (u64*)(ws + o); o += (size_t)SCAN_BLOCKS * 8;
  u32* cdf    = (u32*)(ws + o); o += (size_t)(NB + 4) * 4;
  u32* cstart = (u32*)(ws + o); o += (size_t)(NCHUNKS + 4) * 4;  // NCHUNKS+1 used
  u32* keyRaw = (u32*)(ws + o); o += (size_t)N_ITEMS * 4;
  float* SY   = (float*)(ws + o); o += (size_t)N_ITEMS * 4;
  int* ST     = (int*)(ws + o);   o += (size_t)N_ITEMS * 4;
  int* cnt    = (int*)(ws + o);   o += (size_t)NCHUNKS * 4;

  score_key_kernel<<<SCAN_BLOCKS, 256, 0, stream>>>(x, w1, b1, w2, b2,
                                                    keyRaw, pmin, pmax, hist8, flags);
  hist_kernel<<<SCAN_BLOCKS, 256, 0, stream>>>(keyRaw, pmin, pmax, hist8, mm);
  scan_pav_kernel<<<SCAN_BLOCKS, 256, 0, stream>>>(hist8, flags, cdf, cstart, SY, ST, cnt);
  // 11 tree levels in 2 launches: 0-4 (64 blocks), 5-10 (1 block)
  merge_multi_kernel<<<64, 256, 0, stream>>>(SY, ST, cnt, cstart, 0, 5);
  merge_multi_kernel<<<1, 256, 0, stream>>>(SY, ST, cnt, cstart, 5, 6);
  out_kernel<<<SCAN_BLOCKS, 256, 0, stream>>>(keyRaw, mm, cdf, SY, ST, cnt, out);
}